// Round 7
// baseline (233.230 us; speedup 1.0000x reference)
//
#include <hip/hip_runtime.h>
#include <hip/hip_bf16.h>

#define LQ 2048
#define LV 2048
#define NH 256
#define NB 8

typedef __attribute__((ext_vector_type(4))) float f32x4;
typedef __attribute__((ext_vector_type(8))) short bf16x8;

__device__ __forceinline__ ushort f32_bf16(float x) {
  union { float f; unsigned u; } c; c.f = x;
  unsigned r = (c.u + 0x7FFFu + ((c.u >> 16) & 1u)) >> 16;
  return (ushort)r;
}
__device__ __forceinline__ float bf16_f32(ushort h) {
  union { unsigned u; float f; } c; c.u = ((unsigned)h) << 16;
  return c.f;
}
__device__ __forceinline__ void gl_lds16(const ushort* g, ushort* l) {
  __builtin_amdgcn_global_load_lds(
      (const __attribute__((address_space(1))) unsigned int*)(g),
      (__attribute__((address_space(3))) unsigned int*)(l), 16, 0, 0);
}

// ============================ NEW PATH =====================================

// ---- P0a: hi/lo bf16 decomposition of Q (grid 4096) -----------------------
__global__ __launch_bounds__(256) void k_prepQ(
    const float* __restrict__ Q, ushort* __restrict__ Qh, ushort* __restrict__ Ql) {
  int i = blockIdx.x * 256 + threadIdx.x;
  float4 x = reinterpret_cast<const float4*>(Q)[i];
  ushort4 h, l;
  h.x = f32_bf16(x.x); l.x = f32_bf16(x.x - bf16_f32(h.x));
  h.y = f32_bf16(x.y); l.y = f32_bf16(x.y - bf16_f32(h.y));
  h.z = f32_bf16(x.z); l.z = f32_bf16(x.z - bf16_f32(h.z));
  h.w = f32_bf16(x.w); l.w = f32_bf16(x.w - bf16_f32(h.w));
  reinterpret_cast<ushort4*>(Qh)[i] = h;
  reinterpret_cast<ushort4*>(Ql)[i] = l;
}

// ---- P0b: V -> Vh, Vl (row-major) + VhT (bf16 transpose), one V read ------
__global__ __launch_bounds__(256) void k_prepV(
    const float* __restrict__ V, ushort* __restrict__ Vh, ushort* __restrict__ Vl,
    ushort* __restrict__ VhT) {
  int id = blockIdx.x;
  int b = id & 7, vt = (id >> 3) & 31, ht = id >> 8;
  __shared__ ushort sT[64][72];
  int t = threadIdx.x;
  const size_t base = ((size_t)(b * LV) + vt * 64) * NH + ht * 64;
  int r0 = t >> 4, c4 = (t & 15) << 2;
  #pragma unroll
  for (int it = 0; it < 4; ++it) {
    int r = r0 + it * 16;
    size_t off = base + (size_t)r * NH + c4;
    float4 x = *reinterpret_cast<const float4*>(V + off);
    ushort4 h, l;
    h.x = f32_bf16(x.x); l.x = f32_bf16(x.x - bf16_f32(h.x));
    h.y = f32_bf16(x.y); l.y = f32_bf16(x.y - bf16_f32(h.y));
    h.z = f32_bf16(x.z); l.z = f32_bf16(x.z - bf16_f32(h.z));
    h.w = f32_bf16(x.w); l.w = f32_bf16(x.w - bf16_f32(h.w));
    *reinterpret_cast<ushort4*>(Vh + off) = h;
    *reinterpret_cast<ushort4*>(Vl + off) = l;
    *reinterpret_cast<ushort4*>(&sT[r][c4]) = h;
  }
  __syncthreads();
  int hh = t & 63, vc = t >> 6;
  ushort tmp[16];
  #pragma unroll
  for (int j = 0; j < 16; ++j) tmp[j] = sT[vc * 16 + j][hh];
  ushort* dst = VhT + ((size_t)(b * NH) + ht * 64 + hh) * LV + vt * 64 + vc * 16;
  *reinterpret_cast<ushort4*>(dst)      = *reinterpret_cast<ushort4*>(&tmp[0]);
  *reinterpret_cast<ushort4*>(dst + 4)  = *reinterpret_cast<ushort4*>(&tmp[4]);
  *reinterpret_cast<ushort4*>(dst + 8)  = *reinterpret_cast<ushort4*>(&tmp[8]);
  *reinterpret_cast<ushort4*>(dst + 12) = *reinterpret_cast<ushort4*>(&tmp[12]);
}

// ---- K1: S = Q*V^T (split-bf16 3-MFMA), 8-wave, counted-vmcnt pipeline ----
// grid 2048 = 8 b * 16 qt * 16 vt; 128x128 tile, BK=32, double-buffered.
// PS gets ONE (max, expsum) per row per 128-col tile (width 16).
__global__ __launch_bounds__(512) void k_scores5(
    const ushort* __restrict__ Qh, const ushort* __restrict__ Ql,
    const ushort* __restrict__ Vh, const ushort* __restrict__ Vl,
    float* __restrict__ S, float2* __restrict__ PS) {
  int id = blockIdx.x;
  int b = id & 7, qt = (id >> 3) & 15, vt = id >> 7;
  int t = threadIdx.x, lane = t & 63, w = t >> 6;

  __shared__ ushort lds[2][4][128][32];  // [buf][Qh,Ql,Vh,Vl][row][k] 64KB
  __shared__ float2 part[2][4][64];      // [wq][wv][row64] partials, 4KB

  const size_t bq = (size_t)(b * LQ) + qt * 128;
  const size_t bv = (size_t)(b * LV) + vt * 128;

  // 4 x gl_lds16 per thread per step (512 threads cover 128 rows x 4 cols);
  // source col pre-swizzled (rule #21): LDS dest stays lane-linear.
#define STAGE(buf, kt)                                                      \
  {                                                                         \
    int krow = t >> 2, c = t & 3;                                           \
    int csrc = c ^ ((krow >> 1) & 3);                                       \
    size_t gq = (bq + krow) * NH + (kt) * 32 + csrc * 8;                    \
    size_t gv = (bv + krow) * NH + (kt) * 32 + csrc * 8;                    \
    gl_lds16(Qh + gq, &lds[buf][0][krow][c * 8]);                           \
    gl_lds16(Ql + gq, &lds[buf][1][krow][c * 8]);                           \
    gl_lds16(Vh + gv, &lds[buf][2][krow][c * 8]);                           \
    gl_lds16(Vl + gv, &lds[buf][3][krow][c * 8]);                           \
  }

  int wq = w >> 2, wv = w & 3;           // 2 x 4 wave grid; 64q x 32v / wave
  int ar = wq * 64 + (lane & 15);
  int br = wv * 32 + (lane & 15);
  int kb = lane >> 4;

  f32x4 acc[4][2] = {};

  STAGE(0, 0);
  STAGE(1, 1);

  #pragma unroll
  for (int kt = 0; kt < 8; ++kt) {
    const int cur = kt & 1;
    if (kt < 7) { asm volatile("s_waitcnt vmcnt(4)" ::: "memory"); }
    else        { asm volatile("s_waitcnt vmcnt(0)" ::: "memory"); }
    __builtin_amdgcn_sched_barrier(0);
    __builtin_amdgcn_s_barrier();
    __builtin_amdgcn_sched_barrier(0);

    bf16x8 ah[4], al[4];
    #pragma unroll
    for (int m = 0; m < 4; ++m) {
      int r = ar + m * 16;
      int off = r * 64 + ((kb ^ ((r >> 1) & 3)) << 4);
      ah[m] = *reinterpret_cast<const bf16x8*>((const char*)&lds[cur][0][0][0] + off);
      al[m] = *reinterpret_cast<const bf16x8*>((const char*)&lds[cur][1][0][0] + off);
    }
    __builtin_amdgcn_s_setprio(1);
    #pragma unroll
    for (int n = 0; n < 2; ++n) {
      int r = br + n * 16;
      int off = r * 64 + ((kb ^ ((r >> 1) & 3)) << 4);
      bf16x8 bh = *reinterpret_cast<const bf16x8*>((const char*)&lds[cur][2][0][0] + off);
      bf16x8 bl = *reinterpret_cast<const bf16x8*>((const char*)&lds[cur][3][0][0] + off);
      #pragma unroll
      for (int m = 0; m < 4; ++m) {
        acc[m][n] = __builtin_amdgcn_mfma_f32_16x16x32_bf16(ah[m], bh, acc[m][n], 0, 0, 0);
        acc[m][n] = __builtin_amdgcn_mfma_f32_16x16x32_bf16(ah[m], bl, acc[m][n], 0, 0, 0);
        acc[m][n] = __builtin_amdgcn_mfma_f32_16x16x32_bf16(al[m], bh, acc[m][n], 0, 0, 0);
      }
    }
    __builtin_amdgcn_s_setprio(0);
    __builtin_amdgcn_sched_barrier(0);
    __builtin_amdgcn_s_barrier();
    __builtin_amdgcn_sched_barrier(0);
    if (kt < 6) STAGE(cur, kt + 2);
  }

  // ---- per-row (max, expsum) partials over this wave's 32 cols ----
  #pragma unroll
  for (int m = 0; m < 4; ++m) {
    #pragma unroll
    for (int j = 0; j < 4; ++j) {
      float mx = fmaxf(acc[m][0][j], acc[m][1][j]);
      #pragma unroll
      for (int off = 1; off < 16; off <<= 1) mx = fmaxf(mx, __shfl_xor(mx, off));
      float s = __expf(acc[m][0][j] - mx) + __expf(acc[m][1][j] - mx);
      #pragma unroll
      for (int off = 1; off < 16; off <<= 1) s += __shfl_xor(s, off);
      if ((lane & 15) == 0) {
        int g = lane >> 4;
        float2 v; v.x = mx; v.y = s;
        part[wq][wv][m * 16 + g * 4 + j] = v;
      }
    }
  }
  __syncthreads();
  // merge 4 wv partials -> one (max,sum) per row per 128-col tile
  if (t < 128) {
    int pq = t >> 6, r64 = t & 63;
    float2 p0 = part[pq][0][r64], p1 = part[pq][1][r64];
    float2 p2 = part[pq][2][r64], p3 = part[pq][3][r64];
    float M = fmaxf(fmaxf(p0.x, p1.x), fmaxf(p2.x, p3.x));
    float s = p0.y * __expf(p0.x - M) + p1.y * __expf(p1.x - M)
            + p2.y * __expf(p2.x - M) + p3.y * __expf(p3.x - M);
    float2 v; v.x = M; v.y = s;
    PS[((size_t)(b * LQ) + qt * 128 + t) * 16 + vt] = v;
  }

  // ---- write raw S tile (row-contiguous store order) ----
  float* Sp = S + (size_t)b * LQ * LV + (size_t)(qt * 128 + wq * 64) * LV
            + vt * 128 + wv * 32;
  int rb = (lane >> 4) << 2, c0 = lane & 15;
  #pragma unroll
  for (int m = 0; m < 4; ++m)
    #pragma unroll
    for (int j = 0; j < 4; ++j)
      #pragma unroll
      for (int n = 0; n < 2; ++n)
        Sp[(size_t)(m * 16 + rb + j) * LV + n * 16 + c0] = acc[m][n][j];
#undef STAGE
}

// ---- K2: combine partials + normalize(attn write) + context = P*V ---------
// grid 1024 = 8 b * 128 qstrip(16 rows); 512 threads (8 waves, 16q x 32h)
// -> 4 blocks/CU, ~full occupancy for the 292MB stream.
__global__ __launch_bounds__(512) void k_ctx7(
    const ushort* __restrict__ VhT, const float2* __restrict__ PS,
    float* __restrict__ A, float* __restrict__ C) {
  int id = blockIdx.x;
  int b = id & 7, qs = id >> 3;
  __shared__ float lm[16], li[16];
  __shared__ __align__(16) ushort sP[2][16 * 64];   // swizzled [q][v], 2x2KB

  int t = threadIdx.x, lane = t & 63, w = t >> 6;
  float* Ab = A + (size_t)b * LQ * LV + (size_t)qs * 16 * LV;
  const ushort* Vb = VhT + (size_t)b * NH * LV;

  const int prow = t >> 5, pc = (t & 31) << 1;   // 2 f32 per thread per chunk
  float* aaddr = Ab + (size_t)prow * LV + pc;
  const int poff = (prow * 128 + pc * 2) ^ ((prow & 7) << 4);

  // stats combine: 32 threads/row read the 16 per-tile partials (dup x2)
  {
    int row = t >> 5, seg = t & 31;
    float2 p = PS[((size_t)(b * LQ) + qs * 16 + row) * 16 + (seg & 15)];
    float M = p.x, s = p.y;
    #pragma unroll
    for (int off = 1; off < 16; off <<= 1) {
      float mo = __shfl_xor(M, off), so = __shfl_xor(s, off);
      float mn = fmaxf(M, mo);
      s = s * __expf(M - mn) + so * __expf(mo - mn);
      M = mn;
    }
    if (seg == 0) { lm[row] = M; li[row] = 1.f / s; }
  }
  __syncthreads();

  const float pm = lm[prow], pinv = li[prow];

#define PRODUCE(xv, v0, buf)                                                \
  {                                                                         \
    float2 p;                                                               \
    p.x = __expf((xv).x - pm) * pinv; p.y = __expf((xv).y - pm) * pinv;     \
    *reinterpret_cast<float2*>(aaddr + (v0)) = p;                           \
    ushort2 pk;                                                             \
    pk.x = f32_bf16(p.x); pk.y = f32_bf16(p.y);                             \
    *reinterpret_cast<ushort2*>((char*)&sP[buf][0] + poff) = pk;            \
  }

  // prologue: chunk0 -> sP[0]; prefetch chunk1
  float2 x = *reinterpret_cast<const float2*>(aaddr);
  PRODUCE(x, 0, 0);
  x = *reinterpret_cast<const float2*>(aaddr + 64);
  __syncthreads();

  f32x4 acc[2] = {};
  const int NT = LV / 64;  // 32

  for (int i = 0; i < NT; ++i) {
    const int cur = i & 1;
    const int v0 = i * 64;
    // produce chunk i+1 into the other buffer (x was loaded one iter ago)
    if (i + 1 < NT) PRODUCE(x, v0 + 64, cur ^ 1);
    // issue S prefetch for chunk i+2
    if (i + 2 < NT) x = *reinterpret_cast<const float2*>(aaddr + v0 + 128);

    // MFMA on chunk i from sP[cur]; V frags direct from L2-resident VhT
    #pragma unroll
    for (int ks = 0; ks < 2; ++ks) {
      int vbyte = ks * 64 + ((lane >> 4) << 4);
      int arow = lane & 15;
      bf16x8 pa = *reinterpret_cast<const bf16x8*>(
          (char*)&sP[cur][0] + ((arow * 128 + vbyte) ^ ((arow & 7) << 4)));
      #pragma unroll
      for (int n = 0; n < 2; ++n) {
        int hrow = w * 32 + n * 16 + (lane & 15);
        bf16x8 vb = *reinterpret_cast<const bf16x8*>(
            Vb + (size_t)hrow * LV + v0 + ks * 32 + ((lane >> 4) << 3));
        acc[n] = __builtin_amdgcn_mfma_f32_16x16x32_bf16(pa, vb, acc[n], 0, 0, 0);
      }
    }
    __syncthreads();
  }
#undef PRODUCE

  float* Cb = C + ((size_t)b * LQ + qs * 16) * NH + w * 32;
  int rb = (lane >> 4) << 2, c0 = lane & 15;
  #pragma unroll
  for (int j = 0; j < 4; ++j)
    #pragma unroll
    for (int n = 0; n < 2; ++n)
      Cb[(size_t)(rb + j) * NH + n * 16 + c0] = acc[n][j];
}

// ============================ FALLBACK PATH (round-0) ======================

__global__ __launch_bounds__(256) void k_scores_fb(
    const float* __restrict__ Q, const float* __restrict__ V,
    float* __restrict__ S) {
  int id = blockIdx.x;
  int b = id & 7;
  int inner = id >> 3;
  int qt = inner & 31;
  int vt = inner >> 5;
  __shared__ ushort sQh[64 * 64], sQl[64 * 64], sVh[64 * 64], sVl[64 * 64];
  const float* Qb = Q + (size_t)(b * LQ + qt * 64) * NH;
  const float* Vb = V + (size_t)(b * LV + vt * 64) * NH;
  const int t = threadIdx.x;
  const int lane = t & 63;
  const int w = t >> 6;
  f32x4 acc[4] = {};
  const int row0 = t >> 4;
  const int col4 = (t & 15) << 2;
  for (int kc = 0; kc < 4; ++kc) {
    #pragma unroll
    for (int it = 0; it < 4; ++it) {
      int row = row0 + (it << 4);
      const float4 qx = *reinterpret_cast<const float4*>(Qb + (size_t)row * NH + kc * 64 + col4);
      const float4 vx = *reinterpret_cast<const float4*>(Vb + (size_t)row * NH + kc * 64 + col4);
      int off = ((row * 128 + col4 * 2) ^ ((row & 7) << 4)) >> 1;
      ushort4 h, l;
      h.x = f32_bf16(qx.x); l.x = f32_bf16(qx.x - bf16_f32(h.x));
      h.y = f32_bf16(qx.y); l.y = f32_bf16(qx.y - bf16_f32(h.y));
      h.z = f32_bf16(qx.z); l.z = f32_bf16(qx.z - bf16_f32(h.z));
      h.w = f32_bf16(qx.w); l.w = f32_bf16(qx.w - bf16_f32(h.w));
      *reinterpret_cast<ushort4*>(&sQh[off]) = h;
      *reinterpret_cast<ushort4*>(&sQl[off]) = l;
      h.x = f32_bf16(vx.x); l.x = f32_bf16(vx.x - bf16_f32(h.x));
      h.y = f32_bf16(vx.y); l.y = f32_bf16(vx.y - bf16_f32(h.y));
      h.z = f32_bf16(vx.z); l.z = f32_bf16(vx.z - bf16_f32(h.z));
      h.w = f32_bf16(vx.w); l.w = f32_bf16(vx.w - bf16_f32(h.w));
      *reinterpret_cast<ushort4*>(&sVh[off]) = h;
      *reinterpret_cast<ushort4*>(&sVl[off]) = l;
    }
    __syncthreads();
    int arow = (w << 4) + (lane & 15);
    int abase = arow * 128;
    int aswz = (arow & 7) << 4;
    #pragma unroll
    for (int ks = 0; ks < 2; ++ks) {
      int koffB = (ks << 6) + ((lane >> 4) << 4);
      int aoff = ((abase + koffB) ^ aswz) >> 1;
      bf16x8 ah = *reinterpret_cast<const bf16x8*>(&sQh[aoff]);
      bf16x8 al = *reinterpret_cast<const bf16x8*>(&sQl[aoff]);
      #pragma unroll
      for (int n = 0; n < 4; ++n) {
        int brow = (n << 4) + (lane & 15);
        int boff = (((brow * 128) + koffB) ^ ((brow & 7) << 4)) >> 1;
        bf16x8 bh = *reinterpret_cast<const bf16x8*>(&sVh[boff]);
        bf16x8 bl = *reinterpret_cast<const bf16x8*>(&sVl[boff]);
        acc[n] = __builtin_amdgcn_mfma_f32_16x16x32_bf16(ah, bh, acc[n], 0, 0, 0);
        acc[n] = __builtin_amdgcn_mfma_f32_16x16x32_bf16(ah, bl, acc[n], 0, 0, 0);
        acc[n] = __builtin_amdgcn_mfma_f32_16x16x32_bf16(al, bh, acc[n], 0, 0, 0);
      }
    }
    __syncthreads();
  }
  float* Sp = S + (size_t)b * LQ * LV + (size_t)(qt * 64) * LV + vt * 64;
  int rbase = (w << 4) + ((lane >> 4) << 2);
  int c0 = lane & 15;
  #pragma unroll
  for (int n = 0; n < 4; ++n)
    #pragma unroll
    for (int j = 0; j < 4; ++j)
      Sp[(size_t)(rbase + j) * LV + (n << 4) + c0] = acc[n][j];
}

__global__ __launch_bounds__(256) void k_stats_fb(const float* __restrict__ S,
                                                  float* __restrict__ ml) {
  const size_t r = blockIdx.x;
  const float* row = S + r * LV;
  int t = threadIdx.x;
  float4 a = *reinterpret_cast<const float4*>(row + (t << 2));
  float4 c = *reinterpret_cast<const float4*>(row + 1024 + (t << 2));
  float m = fmaxf(fmaxf(fmaxf(a.x, a.y), fmaxf(a.z, a.w)),
                  fmaxf(fmaxf(c.x, c.y), fmaxf(c.z, c.w)));
  #pragma unroll
  for (int off = 32; off; off >>= 1) m = fmaxf(m, __shfl_xor(m, off));
  __shared__ float redm[4];
  __shared__ float reds[4];
  if ((t & 63) == 0) redm[t >> 6] = m;
  __syncthreads();
  m = fmaxf(fmaxf(redm[0], redm[1]), fmaxf(redm[2], redm[3]));
  float s = __expf(a.x - m) + __expf(a.y - m) + __expf(a.z - m) + __expf(a.w - m)
          + __expf(c.x - m) + __expf(c.y - m) + __expf(c.z - m) + __expf(c.w - m);
  #pragma unroll
  for (int off = 32; off; off >>= 1) s += __shfl_xor(s, off);
  if ((t & 63) == 0) reds[t >> 6] = s;
  __syncthreads();
  if (t == 0) {
    float tot = reds[0] + reds[1] + reds[2] + reds[3];
    ml[2 * r] = m;
    ml[2 * r + 1] = 1.0f / tot;
  }
}

__global__ __launch_bounds__(256) void k_ctx_fb(
    const float* __restrict__ V, const float* __restrict__ ml,
    float* __restrict__ A, float* __restrict__ C) {
  int id = blockIdx.x;
  int b = id & 7;
  int qt = id >> 3;
  __shared__ ushort sP[32 * 40];
  __shared__ ushort sVT[256 * 40];
  __shared__ float lmv[32], liv[32];
  int t = threadIdx.x;
  int lane = t & 63;
  int w = t >> 6;
  int wr = w >> 1, wh = w & 1;
  if (t < 32) {
    size_t r = (size_t)b * LQ + qt * 32 + t;
    lmv[t] = ml[2 * r];
    liv[t] = ml[2 * r + 1];
  }
  __syncthreads();
  f32x4 acc[8] = {};
  float* Ab = A + (size_t)b * LQ * LV + (size_t)(qt * 32) * LV;
  const float* Vb = V + (size_t)b * LV * NH;
  const int prow = t >> 3;
  const int pv4 = (t & 7) << 2;
  for (int v0 = 0; v0 < LV; v0 += 32) {
    {
      float* addr = Ab + (size_t)prow * LV + v0 + pv4;
      float4 s4 = *reinterpret_cast<const float4*>(addr);
      float m = lmv[prow], inv = liv[prow];
      float4 p4;
      p4.x = __expf(s4.x - m) * inv;
      p4.y = __expf(s4.y - m) * inv;
      p4.z = __expf(s4.z - m) * inv;
      p4.w = __expf(s4.w - m) * inv;
      *reinterpret_cast<float4*>(addr) = p4;
      ushort4 pb;
      pb.x = f32_bf16(p4.x); pb.y = f32_bf16(p4.y);
      pb.z = f32_bf16(p4.z); pb.w = f32_bf16(p4.w);
      *reinterpret_cast<ushort4*>(&sP[prow * 40 + pv4]) = pb;
    }
    #pragma unroll 4
    for (int vl = 0; vl < 32; ++vl) {
      float x = Vb[(size_t)(v0 + vl) * NH + t];
      sVT[t * 40 + vl] = f32_bf16(x);
    }
    __syncthreads();
    bf16x8 pa = *reinterpret_cast<const bf16x8*>(
        &sP[((wr << 4) + (lane & 15)) * 40 + ((lane >> 4) << 3)]);
    #pragma unroll
    for (int n = 0; n < 8; ++n) {
      int hrow = (wh << 7) + (n << 4) + (lane & 15);
      bf16x8 vb = *reinterpret_cast<const bf16x8*>(
          &sVT[hrow * 40 + ((lane >> 4) << 3)]);
      acc[n] = __builtin_amdgcn_mfma_f32_16x16x32_bf16(pa, vb, acc[n], 0, 0, 0);
    }
    __syncthreads();
  }
  float* Cb = C + ((size_t)b * LQ + qt * 32) * NH;
  int rbase = (wr << 4) + ((lane >> 4) << 2);
  int c0 = lane & 15;
  #pragma unroll
  for (int n = 0; n < 8; ++n)
    #pragma unroll
    for (int j = 0; j < 4; ++j)
      Cb[(size_t)(rbase + j) * NH + (wh << 7) + (n << 4) + c0] = acc[n][j];
}

// ===========================================================================

extern "C" void kernel_launch(void* const* d_in, const int* in_sizes, int n_in,
                              void* d_out, int out_size, void* d_ws, size_t ws_size,
                              hipStream_t stream) {
  const float* Q = (const float*)d_in[0];
  const float* V = (const float*)d_in[1];
  float* out = (float*)d_out;
  float* C = out;                                  // context: 8*2048*256
  float* A = out + (size_t)NB * LQ * NH;           // attn:    8*2048*2048

  const size_t NE = (size_t)NB * LQ * NH;          // 4,194,304 elems
  const size_t PSN = (size_t)NB * LQ * 16;         // 262,144 float2
  const size_t need = NE * 2 * 5 + PSN * 8;        // ≈ 42 MiB

  if (ws_size >= need) {
    ushort* Qh  = (ushort*)d_ws;
    ushort* Ql  = Qh + NE;
    ushort* Vh  = Ql + NE;
    ushort* Vl  = Vh + NE;
    ushort* VhT = Vl + NE;
    float2* PS  = (float2*)(VhT + NE);
    k_prepQ<<<dim3(NE / 4 / 256), dim3(256), 0, stream>>>(Q, Qh, Ql);
    k_prepV<<<dim3(NB * 32 * 4), dim3(256), 0, stream>>>(V, Vh, Vl, VhT);
    k_scores5<<<dim3(NB * 16 * 16), dim3(512), 0, stream>>>(Qh, Ql, Vh, Vl, A, PS);
    k_ctx7<<<dim3(NB * 128), dim3(512), 0, stream>>>(VhT, PS, A, C);
  } else {
    float* ml = (float*)d_ws;                      // 128 KB fallback scratch
    k_scores_fb<<<dim3(NB * 32 * 32), dim3(256), 0, stream>>>(Q, V, A);
    k_stats_fb<<<dim3(NB * LQ), dim3(256), 0, stream>>>(A, ml);
    k_ctx_fb<<<dim3(NB * 64), dim3(256), 0, stream>>>(V, ml, A, C);
  }
}

// Round 8
// 170.068 us; speedup vs baseline: 1.3714x; 1.3714x over previous
//
#include <hip/hip_runtime.h>
#include <hip/hip_bf16.h>

#define LQ 2048
#define LV 2048
#define NH 256
#define NB 8

typedef __attribute__((ext_vector_type(4))) float f32x4;
typedef __attribute__((ext_vector_type(8))) short bf16x8;

__device__ __forceinline__ ushort f32_bf16(float x) {
  union { float f; unsigned u; } c; c.f = x;
  unsigned r = (c.u + 0x7FFFu + ((c.u >> 16) & 1u)) >> 16;
  return (ushort)r;
}
__device__ __forceinline__ float bf16_f32(ushort h) {
  union { unsigned u; float f; } c; c.u = ((unsigned)h) << 16;
  return c.f;
}
__device__ __forceinline__ void gl_lds16(const ushort* g, ushort* l) {
  __builtin_amdgcn_global_load_lds(
      (const __attribute__((address_space(1))) unsigned int*)(g),
      (__attribute__((address_space(3))) unsigned int*)(l), 16, 0, 0);
}

// ============================ NEW PATH =====================================

// ---- P0a: hi/lo bf16 decomposition of Q (grid 4096) -----------------------
__global__ __launch_bounds__(256) void k_prepQ(
    const float* __restrict__ Q, ushort* __restrict__ Qh, ushort* __restrict__ Ql) {
  int i = blockIdx.x * 256 + threadIdx.x;
  float4 x = reinterpret_cast<const float4*>(Q)[i];
  ushort4 h, l;
  h.x = f32_bf16(x.x); l.x = f32_bf16(x.x - bf16_f32(h.x));
  h.y = f32_bf16(x.y); l.y = f32_bf16(x.y - bf16_f32(h.y));
  h.z = f32_bf16(x.z); l.z = f32_bf16(x.z - bf16_f32(h.z));
  h.w = f32_bf16(x.w); l.w = f32_bf16(x.w - bf16_f32(h.w));
  reinterpret_cast<ushort4*>(Qh)[i] = h;
  reinterpret_cast<ushort4*>(Ql)[i] = l;
}

// ---- P0b: V -> Vh, Vl (row-major) + VhT (bf16 transpose), one V read ------
__global__ __launch_bounds__(256) void k_prepV(
    const float* __restrict__ V, ushort* __restrict__ Vh, ushort* __restrict__ Vl,
    ushort* __restrict__ VhT) {
  int id = blockIdx.x;
  int b = id & 7, vt = (id >> 3) & 31, ht = id >> 8;
  __shared__ ushort sT[64][72];
  int t = threadIdx.x;
  const size_t base = ((size_t)(b * LV) + vt * 64) * NH + ht * 64;
  int r0 = t >> 4, c4 = (t & 15) << 2;
  #pragma unroll
  for (int it = 0; it < 4; ++it) {
    int r = r0 + it * 16;
    size_t off = base + (size_t)r * NH + c4;
    float4 x = *reinterpret_cast<const float4*>(V + off);
    ushort4 h, l;
    h.x = f32_bf16(x.x); l.x = f32_bf16(x.x - bf16_f32(h.x));
    h.y = f32_bf16(x.y); l.y = f32_bf16(x.y - bf16_f32(h.y));
    h.z = f32_bf16(x.z); l.z = f32_bf16(x.z - bf16_f32(h.z));
    h.w = f32_bf16(x.w); l.w = f32_bf16(x.w - bf16_f32(h.w));
    *reinterpret_cast<ushort4*>(Vh + off) = h;
    *reinterpret_cast<ushort4*>(Vl + off) = l;
    *reinterpret_cast<ushort4*>(&sT[r][c4]) = h;
  }
  __syncthreads();
  int hh = t & 63, vc = t >> 6;
  ushort tmp[16];
  #pragma unroll
  for (int j = 0; j < 16; ++j) tmp[j] = sT[vc * 16 + j][hh];
  ushort* dst = VhT + ((size_t)(b * NH) + ht * 64 + hh) * LV + vt * 64 + vc * 16;
  *reinterpret_cast<ushort4*>(dst)      = *reinterpret_cast<ushort4*>(&tmp[0]);
  *reinterpret_cast<ushort4*>(dst + 4)  = *reinterpret_cast<ushort4*>(&tmp[4]);
  *reinterpret_cast<ushort4*>(dst + 8)  = *reinterpret_cast<ushort4*>(&tmp[8]);
  *reinterpret_cast<ushort4*>(dst + 12) = *reinterpret_cast<ushort4*>(&tmp[12]);
}

// ---- K1: S = Q*V^T (split-bf16 3-MFMA), counted-vmcnt depth-2 pipeline ----
// (proven R5 kernel, unchanged)
__global__ __launch_bounds__(256) void k_scores4(
    const ushort* __restrict__ Qh, const ushort* __restrict__ Ql,
    const ushort* __restrict__ Vh, const ushort* __restrict__ Vl,
    float* __restrict__ S, float2* __restrict__ PS) {
  int id = blockIdx.x;
  int b = id & 7, qt = (id >> 3) & 15, vt = id >> 7;
  int t = threadIdx.x, lane = t & 63, w = t >> 6;

  __shared__ ushort lds[2][4][128][32];  // [buf][Qh,Ql,Vh,Vl][row][k] 64KB

  const size_t bq = (size_t)(b * LQ) + qt * 128;
  const size_t bv = (size_t)(b * LV) + vt * 128;

#define STAGE(buf, kt)                                                      \
  {                                                                         \
    int krow = t >> 2, c = t & 3;                                           \
    _Pragma("unroll")                                                       \
    for (int hh = 0; hh < 2; ++hh) {                                        \
      int row = hh * 64 + krow;                                             \
      int csrc = c ^ ((row >> 1) & 3);                                      \
      size_t gq = (bq + row) * NH + (kt) * 32 + csrc * 8;                   \
      size_t gv = (bv + row) * NH + (kt) * 32 + csrc * 8;                   \
      gl_lds16(Qh + gq, &lds[buf][0][row][c * 8]);                          \
      gl_lds16(Ql + gq, &lds[buf][1][row][c * 8]);                          \
      gl_lds16(Vh + gv, &lds[buf][2][row][c * 8]);                          \
      gl_lds16(Vl + gv, &lds[buf][3][row][c * 8]);                          \
    }                                                                       \
  }

  int wq = w >> 1, wv = w & 1;
  int ar = wq * 64 + (lane & 15);
  int br = wv * 64 + (lane & 15);
  int kb = lane >> 4;

  f32x4 acc[4][4] = {};

  STAGE(0, 0);
  STAGE(1, 1);

  #pragma unroll
  for (int kt = 0; kt < 8; ++kt) {
    const int cur = kt & 1;
    if (kt < 7) { asm volatile("s_waitcnt vmcnt(8)" ::: "memory"); }
    else        { asm volatile("s_waitcnt vmcnt(0)" ::: "memory"); }
    __builtin_amdgcn_sched_barrier(0);
    __builtin_amdgcn_s_barrier();
    __builtin_amdgcn_sched_barrier(0);

    bf16x8 ah[4], al[4];
    #pragma unroll
    for (int m = 0; m < 4; ++m) {
      int r = ar + m * 16;
      int off = r * 64 + ((kb ^ ((r >> 1) & 3)) << 4);
      ah[m] = *reinterpret_cast<const bf16x8*>((const char*)&lds[cur][0][0][0] + off);
      al[m] = *reinterpret_cast<const bf16x8*>((const char*)&lds[cur][1][0][0] + off);
    }
    __builtin_amdgcn_s_setprio(1);
    #pragma unroll
    for (int n = 0; n < 4; ++n) {
      int r = br + n * 16;
      int off = r * 64 + ((kb ^ ((r >> 1) & 3)) << 4);
      bf16x8 bh = *reinterpret_cast<const bf16x8*>((const char*)&lds[cur][2][0][0] + off);
      bf16x8 bl = *reinterpret_cast<const bf16x8*>((const char*)&lds[cur][3][0][0] + off);
      #pragma unroll
      for (int m = 0; m < 4; ++m) {
        acc[m][n] = __builtin_amdgcn_mfma_f32_16x16x32_bf16(ah[m], bh, acc[m][n], 0, 0, 0);
        acc[m][n] = __builtin_amdgcn_mfma_f32_16x16x32_bf16(ah[m], bl, acc[m][n], 0, 0, 0);
        acc[m][n] = __builtin_amdgcn_mfma_f32_16x16x32_bf16(al[m], bh, acc[m][n], 0, 0, 0);
      }
    }
    __builtin_amdgcn_s_setprio(0);
    __builtin_amdgcn_sched_barrier(0);
    __builtin_amdgcn_s_barrier();
    __builtin_amdgcn_sched_barrier(0);
    if (kt < 6) STAGE(cur, kt + 2);
  }

  // ---- per-row (max, expsum) partials over this wave's 64 cols ----
  float M[4][4], Sx[4][4];
  #pragma unroll
  for (int m = 0; m < 4; ++m) {
    #pragma unroll
    for (int j = 0; j < 4; ++j) {
      float mx = fmaxf(fmaxf(acc[m][0][j], acc[m][1][j]),
                       fmaxf(acc[m][2][j], acc[m][3][j]));
      #pragma unroll
      for (int off = 1; off < 16; off <<= 1) mx = fmaxf(mx, __shfl_xor(mx, off));
      float s = __expf(acc[m][0][j] - mx) + __expf(acc[m][1][j] - mx)
              + __expf(acc[m][2][j] - mx) + __expf(acc[m][3][j] - mx);
      #pragma unroll
      for (int off = 1; off < 16; off <<= 1) s += __shfl_xor(s, off);
      M[m][j] = mx; Sx[m][j] = s;
    }
  }
  if ((lane & 15) == 0) {
    int g = lane >> 4;
    float2* ps = PS + ((size_t)(b * LQ) + qt * 128 + wq * 64) * 32 + vt * 2 + wv;
    #pragma unroll
    for (int m = 0; m < 4; ++m)
      #pragma unroll
      for (int j = 0; j < 4; ++j) {
        int r = m * 16 + g * 4 + j;
        float2 v; v.x = M[m][j]; v.y = Sx[m][j];
        ps[(size_t)r * 32] = v;
      }
  }

  // ---- write raw S tile (row-contiguous store order) ----
  float* Sp = S + (size_t)b * LQ * LV + (size_t)(qt * 128 + wq * 64) * LV
            + vt * 128 + wv * 64;
  int rb = (lane >> 4) << 2, c0 = lane & 15;
  #pragma unroll
  for (int m = 0; m < 4; ++m)
    #pragma unroll
    for (int j = 0; j < 4; ++j)
      #pragma unroll
      for (int n = 0; n < 4; ++n)
        Sp[(size_t)(m * 16 + rb + j) * LV + n * 16 + c0] = acc[m][n][j];
#undef STAGE
}

// ---- K2: combine partials + normalize(attn write) + context = P*V ---------
// grid 512 = 8 b * 64 qstrip(32 rows); 512 threads (8 waves, 32q x 32h each)
// PAIRED v-chunks: 4 sP buffers, one __syncthreads per 128 cols (was 64).
// Per-chunk layout/swizzle byte-identical to proven ctx6.
__global__ __launch_bounds__(512) void k_ctx8(
    const ushort* __restrict__ VhT, const float2* __restrict__ PS,
    float* __restrict__ A, float* __restrict__ C) {
  int id = blockIdx.x;
  int b = id & 7, qs = id >> 3;
  __shared__ float lm[32], li[32];
  __shared__ __align__(16) ushort sP[4][32 * 64];   // swizzled [q][v], 4x4KB

  int t = threadIdx.x, lane = t & 63, w = t >> 6;
  float* Ab = A + (size_t)b * LQ * LV + (size_t)qs * 32 * LV;
  const ushort* Vb = VhT + (size_t)b * NH * LV;

  const int prow = t >> 4, pc = (t & 15) << 2;   // 4 f32 per thread per chunk
  float* aaddr = Ab + (size_t)prow * LV + pc;
  const int poff = (prow * 128 + pc * 2) ^ ((prow & 7) << 4);

  // stats combine: 16 threads/row, 2 partials each, 16-lane reduce
  {
    int row = t >> 4, seg = t & 15;
    const float2* pp = PS + ((size_t)(b * LQ) + qs * 32 + row) * 32 + seg * 2;
    float2 p0 = pp[0], p1 = pp[1];
    float M = fmaxf(p0.x, p1.x);
    float s = p0.y * __expf(p0.x - M) + p1.y * __expf(p1.x - M);
    #pragma unroll
    for (int off = 1; off < 16; off <<= 1) {
      float mo = __shfl_xor(M, off), so = __shfl_xor(s, off);
      float mn = fmaxf(M, mo);
      s = s * __expf(M - mn) + so * __expf(mo - mn);
      M = mn;
    }
    if (seg == 0) { lm[row] = M; li[row] = 1.f / s; }
  }
  __syncthreads();

  const float pm = lm[prow], pinv = li[prow];

#define PRODUCE(xv, v0, buf)                                                \
  {                                                                         \
    float4 p;                                                               \
    p.x = __expf((xv).x - pm) * pinv; p.y = __expf((xv).y - pm) * pinv;     \
    p.z = __expf((xv).z - pm) * pinv; p.w = __expf((xv).w - pm) * pinv;     \
    *reinterpret_cast<float4*>(aaddr + (v0)) = p;                           \
    ushort4 pk;                                                             \
    pk.x = f32_bf16(p.x); pk.y = f32_bf16(p.y);                             \
    pk.z = f32_bf16(p.z); pk.w = f32_bf16(p.w);                             \
    *reinterpret_cast<ushort4*>((char*)&sP[buf][0] + poff) = pk;            \
  }

  // prologue: chunks 0,1 -> sP[0],sP[1]; prefetch chunks 2,3
  float4 x0 = *reinterpret_cast<const float4*>(aaddr);
  float4 x1 = *reinterpret_cast<const float4*>(aaddr + 64);
  PRODUCE(x0, 0, 0);
  PRODUCE(x1, 64, 1);
  x0 = *reinterpret_cast<const float4*>(aaddr + 128);
  x1 = *reinterpret_cast<const float4*>(aaddr + 192);
  __syncthreads();

  f32x4 acc[2][2] = {};
  const int NP = LV / 128;  // 16 pairs

  for (int p = 0; p < NP; ++p) {
    const int cur = (p & 1) << 1;        // bufs cur, cur+1 hold pair p
    const int nxt = cur ^ 2;
    const int v0 = p * 128;
    // produce pair p+1 into the other buffer pair (x0/x1 loaded last iter)
    if (p + 1 < NP) {
      PRODUCE(x0, v0 + 128, nxt);
      PRODUCE(x1, v0 + 192, nxt + 1);
    }
    // issue S prefetch for pair p+2
    if (p + 2 < NP) {
      x0 = *reinterpret_cast<const float4*>(aaddr + v0 + 256);
      x1 = *reinterpret_cast<const float4*>(aaddr + v0 + 320);
    }

    // MFMA on pair p from sP[cur], sP[cur+1]; V frags direct from VhT (L2)
    #pragma unroll
    for (int c = 0; c < 2; ++c) {
      #pragma unroll
      for (int ks = 0; ks < 2; ++ks) {
        int vbyte = ks * 64 + ((lane >> 4) << 4);
        bf16x8 pa[2];
        #pragma unroll
        for (int i2 = 0; i2 < 2; ++i2) {
          int arow = i2 * 16 + (lane & 15);
          pa[i2] = *reinterpret_cast<const bf16x8*>(
              (char*)&sP[cur + c][0] + ((arow * 128 + vbyte) ^ ((arow & 7) << 4)));
        }
        #pragma unroll
        for (int n = 0; n < 2; ++n) {
          int hrow = w * 32 + n * 16 + (lane & 15);
          bf16x8 vb = *reinterpret_cast<const bf16x8*>(
              Vb + (size_t)hrow * LV + v0 + c * 64 + ks * 32 + ((lane >> 4) << 3));
          #pragma unroll
          for (int i2 = 0; i2 < 2; ++i2)
            acc[i2][n] = __builtin_amdgcn_mfma_f32_16x16x32_bf16(pa[i2], vb, acc[i2][n], 0, 0, 0);
        }
      }
    }
    __syncthreads();
  }
#undef PRODUCE

  float* Cb = C + ((size_t)b * LQ + qs * 32) * NH + w * 32;
  int rb = (lane >> 4) << 2, c0 = lane & 15;
  #pragma unroll
  for (int i2 = 0; i2 < 2; ++i2)
    #pragma unroll
    for (int j = 0; j < 4; ++j)
      #pragma unroll
      for (int n = 0; n < 2; ++n)
        Cb[(size_t)(i2 * 16 + rb + j) * NH + n * 16 + c0] = acc[i2][n][j];
}

// ============================ FALLBACK PATH (round-0) ======================

__global__ __launch_bounds__(256) void k_scores_fb(
    const float* __restrict__ Q, const float* __restrict__ V,
    float* __restrict__ S) {
  int id = blockIdx.x;
  int b = id & 7;
  int inner = id >> 3;
  int qt = inner & 31;
  int vt = inner >> 5;
  __shared__ ushort sQh[64 * 64], sQl[64 * 64], sVh[64 * 64], sVl[64 * 64];
  const float* Qb = Q + (size_t)(b * LQ + qt * 64) * NH;
  const float* Vb = V + (size_t)(b * LV + vt * 64) * NH;
  const int t = threadIdx.x;
  const int lane = t & 63;
  const int w = t >> 6;
  f32x4 acc[4] = {};
  const int row0 = t >> 4;
  const int col4 = (t & 15) << 2;
  for (int kc = 0; kc < 4; ++kc) {
    #pragma unroll
    for (int it = 0; it < 4; ++it) {
      int row = row0 + (it << 4);
      const float4 qx = *reinterpret_cast<const float4*>(Qb + (size_t)row * NH + kc * 64 + col4);
      const float4 vx = *reinterpret_cast<const float4*>(Vb + (size_t)row * NH + kc * 64 + col4);
      int off = ((row * 128 + col4 * 2) ^ ((row & 7) << 4)) >> 1;
      ushort4 h, l;
      h.x = f32_bf16(qx.x); l.x = f32_bf16(qx.x - bf16_f32(h.x));
      h.y = f32_bf16(qx.y); l.y = f32_bf16(qx.y - bf16_f32(h.y));
      h.z = f32_bf16(qx.z); l.z = f32_bf16(qx.z - bf16_f32(h.z));
      h.w = f32_bf16(qx.w); l.w = f32_bf16(qx.w - bf16_f32(h.w));
      *reinterpret_cast<ushort4*>(&sQh[off]) = h;
      *reinterpret_cast<ushort4*>(&sQl[off]) = l;
      h.x = f32_bf16(vx.x); l.x = f32_bf16(vx.x - bf16_f32(h.x));
      h.y = f32_bf16(vx.y); l.y = f32_bf16(vx.y - bf16_f32(h.y));
      h.z = f32_bf16(vx.z); l.z = f32_bf16(vx.z - bf16_f32(h.z));
      h.w = f32_bf16(vx.w); l.w = f32_bf16(vx.w - bf16_f32(h.w));
      *reinterpret_cast<ushort4*>(&sVh[off]) = h;
      *reinterpret_cast<ushort4*>(&sVl[off]) = l;
    }
    __syncthreads();
    int arow = (w << 4) + (lane & 15);
    int abase = arow * 128;
    int aswz = (arow & 7) << 4;
    #pragma unroll
    for (int ks = 0; ks < 2; ++ks) {
      int koffB = (ks << 6) + ((lane >> 4) << 4);
      int aoff = ((abase + koffB) ^ aswz) >> 1;
      bf16x8 ah = *reinterpret_cast<const bf16x8*>(&sQh[aoff]);
      bf16x8 al = *reinterpret_cast<const bf16x8*>(&sQl[aoff]);
      #pragma unroll
      for (int n = 0; n < 4; ++n) {
        int brow = (n << 4) + (lane & 15);
        int boff = (((brow * 128) + koffB) ^ ((brow & 7) << 4)) >> 1;
        bf16x8 bh = *reinterpret_cast<const bf16x8*>(&sVh[boff]);
        bf16x8 bl = *reinterpret_cast<const bf16x8*>(&sVl[boff]);
        acc[n] = __builtin_amdgcn_mfma_f32_16x16x32_bf16(ah, bh, acc[n], 0, 0, 0);
        acc[n] = __builtin_amdgcn_mfma_f32_16x16x32_bf16(ah, bl, acc[n], 0, 0, 0);
        acc[n] = __builtin_amdgcn_mfma_f32_16x16x32_bf16(al, bh, acc[n], 0, 0, 0);
      }
    }
    __syncthreads();
  }
  float* Sp = S + (size_t)b * LQ * LV + (size_t)(qt * 64) * LV + vt * 64;
  int rbase = (w << 4) + ((lane >> 4) << 2);
  int c0 = lane & 15;
  #pragma unroll
  for (int n = 0; n < 4; ++n)
    #pragma unroll
    for (int j = 0; j < 4; ++j)
      Sp[(size_t)(rbase + j) * LV + (n << 4) + c0] = acc[n][j];
}

__global__ __launch_bounds__(256) void k_stats_fb(const float* __restrict__ S,
                                                  float* __restrict__ ml) {
  const size_t r = blockIdx.x;
  const float* row = S + r * LV;
  int t = threadIdx.x;
  float4 a = *reinterpret_cast<const float4*>(row + (t << 2));
  float4 c = *reinterpret_cast<const float4*>(row + 1024 + (t << 2));
  float m = fmaxf(fmaxf(fmaxf(a.x, a.y), fmaxf(a.z, a.w)),
                  fmaxf(fmaxf(c.x, c.y), fmaxf(c.z, c.w)));
  #pragma unroll
  for (int off = 32; off; off >>= 1) m = fmaxf(m, __shfl_xor(m, off));
  __shared__ float redm[4];
  __shared__ float reds[4];
  if ((t & 63) == 0) redm[t >> 6] = m;
  __syncthreads();
  m = fmaxf(fmaxf(redm[0], redm[1]), fmaxf(redm[2], redm[3]));
  float s = __expf(a.x - m) + __expf(a.y - m) + __expf(a.z - m) + __expf(a.w - m)
          + __expf(c.x - m) + __expf(c.y - m) + __expf(c.z - m) + __expf(c.w - m);
  #pragma unroll
  for (int off = 32; off; off >>= 1) s += __shfl_xor(s, off);
  if ((t & 63) == 0) reds[t >> 6] = s;
  __syncthreads();
  if (t == 0) {
    float tot = reds[0] + reds[1] + reds[2] + reds[3];
    ml[2 * r] = m;
    ml[2 * r + 1] = 1.0f / tot;
  }
}

__global__ __launch_bounds__(256) void k_ctx_fb(
    const float* __restrict__ V, const float* __restrict__ ml,
    float* __restrict__ A, float* __restrict__ C) {
  int id = blockIdx.x;
  int b = id & 7;
  int qt = id >> 3;
  __shared__ ushort sP[32 * 40];
  __shared__ ushort sVT[256 * 40];
  __shared__ float lmv[32], liv[32];
  int t = threadIdx.x;
  int lane = t & 63;
  int w = t >> 6;
  int wr = w >> 1, wh = w & 1;
  if (t < 32) {
    size_t r = (size_t)b * LQ + qt * 32 + t;
    lmv[t] = ml[2 * r];
    liv[t] = ml[2 * r + 1];
  }
  __syncthreads();
  f32x4 acc[8] = {};
  float* Ab = A + (size_t)b * LQ * LV + (size_t)(qt * 32) * LV;
  const float* Vb = V + (size_t)b * LV * NH;
  const int prow = t >> 3;
  const int pv4 = (t & 7) << 2;
  for (int v0 = 0; v0 < LV; v0 += 32) {
    {
      float* addr = Ab + (size_t)prow * LV + v0 + pv4;
      float4 s4 = *reinterpret_cast<const float4*>(addr);
      float m = lmv[prow], inv = liv[prow];
      float4 p4;
      p4.x = __expf(s4.x - m) * inv;
      p4.y = __expf(s4.y - m) * inv;
      p4.z = __expf(s4.z - m) * inv;
      p4.w = __expf(s4.w - m) * inv;
      *reinterpret_cast<float4*>(addr) = p4;
      ushort4 pb;
      pb.x = f32_bf16(p4.x); pb.y = f32_bf16(p4.y);
      pb.z = f32_bf16(p4.z); pb.w = f32_bf16(p4.w);
      *reinterpret_cast<ushort4*>(&sP[prow * 40 + pv4]) = pb;
    }
    #pragma unroll 4
    for (int vl = 0; vl < 32; ++vl) {
      float x = Vb[(size_t)(v0 + vl) * NH + t];
      sVT[t * 40 + vl] = f32_bf16(x);
    }
    __syncthreads();
    bf16x8 pa = *reinterpret_cast<const bf16x8*>(
        &sP[((wr << 4) + (lane & 15)) * 40 + ((lane >> 4) << 3)]);
    #pragma unroll
    for (int n = 0; n < 8; ++n) {
      int hrow = (wh << 7) + (n << 4) + (lane & 15);
      bf16x8 vb = *reinterpret_cast<const bf16x8*>(
          &sVT[hrow * 40 + ((lane >> 4) << 3)]);
      acc[n] = __builtin_amdgcn_mfma_f32_16x16x32_bf16(pa, vb, acc[n], 0, 0, 0);
    }
    __syncthreads();
  }
  float* Cb = C + ((size_t)b * LQ + qt * 32) * NH;
  int rbase = (wr << 4) + ((lane >> 4) << 2);
  int c0 = lane & 15;
  #pragma unroll
  for (int n = 0; n < 8; ++n)
    #pragma unroll
    for (int j = 0; j < 4; ++j)
      Cb[(size_t)(rbase + j) * NH + (wh << 7) + (n << 4) + c0] = acc[n][j];
}

// ===========================================================================

extern "C" void kernel_launch(void* const* d_in, const int* in_sizes, int n_in,
                              void* d_out, int out_size, void* d_ws, size_t ws_size,
                              hipStream_t stream) {
  const float* Q = (const float*)d_in[0];
  const float* V = (const float*)d_in[1];
  float* out = (float*)d_out;
  float* C = out;                                  // context: 8*2048*256
  float* A = out + (size_t)NB * LQ * NH;           // attn:    8*2048*2048

  const size_t NE = (size_t)NB * LQ * NH;          // 4,194,304 elems
  const size_t PSN = (size_t)NB * LQ * 32;         // 524,288 float2
  const size_t need = NE * 2 * 5 + PSN * 8;        // ≈ 46.1 MiB

  if (ws_size >= need) {
    ushort* Qh  = (ushort*)d_ws;
    ushort* Ql  = Qh + NE;
    ushort* Vh  = Ql + NE;
    ushort* Vl  = Vh + NE;
    ushort* VhT = Vl + NE;
    float2* PS  = (float2*)(VhT + NE);
    k_prepQ<<<dim3(NE / 4 / 256), dim3(256), 0, stream>>>(Q, Qh, Ql);
    k_prepV<<<dim3(NB * 32 * 4), dim3(256), 0, stream>>>(V, Vh, Vl, VhT);
    k_scores4<<<dim3(NB * 16 * 16), dim3(256), 0, stream>>>(Qh, Ql, Vh, Vl, A, PS);
    k_ctx8<<<dim3(NB * 64), dim3(512), 0, stream>>>(VhT, PS, A, C);
  } else {
    float* ml = (float*)d_ws;                      // 128 KB fallback scratch
    k_scores_fb<<<dim3(NB * 32 * 32), dim3(256), 0, stream>>>(Q, V, A);
    k_stats_fb<<<dim3(NB * LQ), dim3(256), 0, stream>>>(A, ml);
    k_ctx_fb<<<dim3(NB * 64), dim3(256), 0, stream>>>(V, ml, A, C);
  }
}

// Round 9
// 161.063 us; speedup vs baseline: 1.4481x; 1.0559x over previous
//
#include <hip/hip_runtime.h>
#include <hip/hip_bf16.h>

#define LQ 2048
#define LV 2048
#define NH 256
#define NB 8

typedef __attribute__((ext_vector_type(4))) float f32x4;
typedef __attribute__((ext_vector_type(8))) short bf16x8;

__device__ __forceinline__ ushort f32_bf16(float x) {
  union { float f; unsigned u; } c; c.f = x;
  unsigned r = (c.u + 0x7FFFu + ((c.u >> 16) & 1u)) >> 16;
  return (ushort)r;
}
__device__ __forceinline__ float bf16_f32(ushort h) {
  union { unsigned u; float f; } c; c.u = ((unsigned)h) << 16;
  return c.f;
}
__device__ __forceinline__ void gl_lds16(const ushort* g, ushort* l) {
  __builtin_amdgcn_global_load_lds(
      (const __attribute__((address_space(1))) unsigned int*)(g),
      (__attribute__((address_space(3))) unsigned int*)(l), 16, 0, 0);
}

// ============================ NEW PATH =====================================

// ---- P0a: hi/lo bf16 decomposition of Q (grid 4096) -----------------------
__global__ __launch_bounds__(256) void k_prepQ(
    const float* __restrict__ Q, ushort* __restrict__ Qh, ushort* __restrict__ Ql) {
  int i = blockIdx.x * 256 + threadIdx.x;
  float4 x = reinterpret_cast<const float4*>(Q)[i];
  ushort4 h, l;
  h.x = f32_bf16(x.x); l.x = f32_bf16(x.x - bf16_f32(h.x));
  h.y = f32_bf16(x.y); l.y = f32_bf16(x.y - bf16_f32(h.y));
  h.z = f32_bf16(x.z); l.z = f32_bf16(x.z - bf16_f32(h.z));
  h.w = f32_bf16(x.w); l.w = f32_bf16(x.w - bf16_f32(h.w));
  reinterpret_cast<ushort4*>(Qh)[i] = h;
  reinterpret_cast<ushort4*>(Ql)[i] = l;
}

// ---- P0b: V -> Vh, Vl (row-major) + VhT (bf16 transpose), one V read ------
__global__ __launch_bounds__(256) void k_prepV(
    const float* __restrict__ V, ushort* __restrict__ Vh, ushort* __restrict__ Vl,
    ushort* __restrict__ VhT) {
  int id = blockIdx.x;
  int b = id & 7, vt = (id >> 3) & 31, ht = id >> 8;
  __shared__ ushort sT[64][72];
  int t = threadIdx.x;
  const size_t base = ((size_t)(b * LV) + vt * 64) * NH + ht * 64;
  int r0 = t >> 4, c4 = (t & 15) << 2;
  #pragma unroll
  for (int it = 0; it < 4; ++it) {
    int r = r0 + it * 16;
    size_t off = base + (size_t)r * NH + c4;
    float4 x = *reinterpret_cast<const float4*>(V + off);
    ushort4 h, l;
    h.x = f32_bf16(x.x); l.x = f32_bf16(x.x - bf16_f32(h.x));
    h.y = f32_bf16(x.y); l.y = f32_bf16(x.y - bf16_f32(h.y));
    h.z = f32_bf16(x.z); l.z = f32_bf16(x.z - bf16_f32(h.z));
    h.w = f32_bf16(x.w); l.w = f32_bf16(x.w - bf16_f32(h.w));
    *reinterpret_cast<ushort4*>(Vh + off) = h;
    *reinterpret_cast<ushort4*>(Vl + off) = l;
    *reinterpret_cast<ushort4*>(&sT[r][c4]) = h;
  }
  __syncthreads();
  int hh = t & 63, vc = t >> 6;
  ushort tmp[16];
  #pragma unroll
  for (int j = 0; j < 16; ++j) tmp[j] = sT[vc * 16 + j][hh];
  ushort* dst = VhT + ((size_t)(b * NH) + ht * 64 + hh) * LV + vt * 64 + vc * 16;
  *reinterpret_cast<ushort4*>(dst)      = *reinterpret_cast<ushort4*>(&tmp[0]);
  *reinterpret_cast<ushort4*>(dst + 4)  = *reinterpret_cast<ushort4*>(&tmp[4]);
  *reinterpret_cast<ushort4*>(dst + 8)  = *reinterpret_cast<ushort4*>(&tmp[8]);
  *reinterpret_cast<ushort4*>(dst + 12) = *reinterpret_cast<ushort4*>(&tmp[12]);
}

// ---- K1: S = Q*V^T, 256x256 block, 8 waves of 64x128, 128KB dynamic LDS ---
// grid 512 = 8 b * 8 qt * 8 vt; BK=32, double-buffered, counted-vmcnt.
// PS: one (max, expsum) per row per 128-col half-tile (width 16 per row).
__global__ __launch_bounds__(512) void k_scores6(
    const ushort* __restrict__ Qh, const ushort* __restrict__ Ql,
    const ushort* __restrict__ Vh, const ushort* __restrict__ Vl,
    float* __restrict__ S, float2* __restrict__ PS) {
  extern __shared__ ushort dynlds[];  // [buf2][arr4][row256][col32] = 128KB
  int id = blockIdx.x;
  int b = id & 7, qt = (id >> 3) & 7, vt = id >> 6;
  int t = threadIdx.x, lane = t & 63, w = t >> 6;

  const size_t bq = (size_t)(b * LQ) + qt * 256;
  const size_t bv = (size_t)(b * LV) + vt * 256;

  // byte offset into dynlds: row stride 64B
#define LBASE(buf, arr) ((char*)dynlds + ((buf) * 4 + (arr)) * (256 * 64))

  // 8 x gl_lds16/thread: 512 threads cover 256 rows x 4 cols for Q and V;
  // source col pre-swizzled (rule #21), LDS dest lane-linear (base + t*16).
#define STAGE(buf, kt)                                                      \
  {                                                                         \
    int krow = t >> 2, c = t & 3;                                           \
    _Pragma("unroll")                                                       \
    for (int hh = 0; hh < 2; ++hh) {                                        \
      int row = hh * 128 + krow;                                            \
      int csrc = c ^ ((row >> 1) & 3);                                      \
      size_t gq = (bq + row) * NH + (kt) * 32 + csrc * 8;                   \
      size_t gv = (bv + row) * NH + (kt) * 32 + csrc * 8;                   \
      gl_lds16(Qh + gq, (ushort*)(LBASE(buf, 0) + row * 64 + c * 16));      \
      gl_lds16(Ql + gq, (ushort*)(LBASE(buf, 1) + row * 64 + c * 16));      \
      gl_lds16(Vh + gv, (ushort*)(LBASE(buf, 2) + row * 64 + c * 16));      \
      gl_lds16(Vl + gv, (ushort*)(LBASE(buf, 3) + row * 64 + c * 16));      \
    }                                                                       \
  }

  int wq = w >> 1, wv = w & 1;           // 4x2 wave grid; 64q x 128v / wave
  int ar = wq * 64 + (lane & 15);
  int br = wv * 128 + (lane & 15);
  int kb = lane >> 4;

  f32x4 acc[4][8] = {};

  STAGE(0, 0);
  STAGE(1, 1);

  #pragma unroll
  for (int kt = 0; kt < 8; ++kt) {
    const int cur = kt & 1;
    if (kt < 7) { asm volatile("s_waitcnt vmcnt(8)" ::: "memory"); }
    else        { asm volatile("s_waitcnt vmcnt(0)" ::: "memory"); }
    __builtin_amdgcn_sched_barrier(0);
    __builtin_amdgcn_s_barrier();
    __builtin_amdgcn_sched_barrier(0);

    bf16x8 ah[4], al[4];
    #pragma unroll
    for (int m = 0; m < 4; ++m) {
      int r = ar + m * 16;
      int off = r * 64 + ((kb ^ ((r >> 1) & 3)) << 4);
      ah[m] = *reinterpret_cast<const bf16x8*>(LBASE(cur, 0) + off);
      al[m] = *reinterpret_cast<const bf16x8*>(LBASE(cur, 1) + off);
    }
    __builtin_amdgcn_s_setprio(1);
    #pragma unroll
    for (int n = 0; n < 8; ++n) {
      int r = br + n * 16;
      int off = r * 64 + ((kb ^ ((r >> 1) & 3)) << 4);
      bf16x8 bh = *reinterpret_cast<const bf16x8*>(LBASE(cur, 2) + off);
      bf16x8 bl = *reinterpret_cast<const bf16x8*>(LBASE(cur, 3) + off);
      #pragma unroll
      for (int m = 0; m < 4; ++m) {
        acc[m][n] = __builtin_amdgcn_mfma_f32_16x16x32_bf16(ah[m], bh, acc[m][n], 0, 0, 0);
        acc[m][n] = __builtin_amdgcn_mfma_f32_16x16x32_bf16(ah[m], bl, acc[m][n], 0, 0, 0);
        acc[m][n] = __builtin_amdgcn_mfma_f32_16x16x32_bf16(al[m], bh, acc[m][n], 0, 0, 0);
      }
    }
    __builtin_amdgcn_s_setprio(0);
    __builtin_amdgcn_sched_barrier(0);
    __builtin_amdgcn_s_barrier();
    __builtin_amdgcn_sched_barrier(0);
    if (kt < 6) STAGE(cur, kt + 2);
  }

  // ---- per-row (max, expsum) partials over this wave's 128 cols ----
  #pragma unroll
  for (int m = 0; m < 4; ++m) {
    #pragma unroll
    for (int j = 0; j < 4; ++j) {
      float mx = acc[m][0][j];
      #pragma unroll
      for (int n = 1; n < 8; ++n) mx = fmaxf(mx, acc[m][n][j]);
      #pragma unroll
      for (int off = 1; off < 16; off <<= 1) mx = fmaxf(mx, __shfl_xor(mx, off));
      float s = 0.f;
      #pragma unroll
      for (int n = 0; n < 8; ++n) s += __expf(acc[m][n][j] - mx);
      #pragma unroll
      for (int off = 1; off < 16; off <<= 1) s += __shfl_xor(s, off);
      if ((lane & 15) == 0) {
        int g = lane >> 4;
        int row = wq * 64 + m * 16 + g * 4 + j;
        float2 v; v.x = mx; v.y = s;
        PS[((size_t)(b * LQ) + qt * 256 + row) * 16 + vt * 2 + wv] = v;
      }
    }
  }

  // ---- write raw S tile (row-contiguous store order) ----
  float* Sp = S + (size_t)b * LQ * LV + (size_t)(qt * 256 + wq * 64) * LV
            + vt * 256 + wv * 128;
  int rb = (lane >> 4) << 2, c0 = lane & 15;
  #pragma unroll
  for (int m = 0; m < 4; ++m)
    #pragma unroll
    for (int j = 0; j < 4; ++j)
      #pragma unroll
      for (int n = 0; n < 8; ++n)
        Sp[(size_t)(m * 16 + rb + j) * LV + n * 16 + c0] = acc[m][n][j];
#undef STAGE
#undef LBASE
}

// ---- K2: combine partials + normalize(attn write) + context = P*V ---------
// grid 512 = 8 b * 64 qstrip(32 rows); 512 threads (8 waves, 32q x 32h each)
// PAIRED v-chunks (proven R7 kernel); stats combine reads 16-wide PS.
__global__ __launch_bounds__(512) void k_ctx8(
    const ushort* __restrict__ VhT, const float2* __restrict__ PS,
    float* __restrict__ A, float* __restrict__ C) {
  int id = blockIdx.x;
  int b = id & 7, qs = id >> 3;
  __shared__ float lm[32], li[32];
  __shared__ __align__(16) ushort sP[4][32 * 64];   // swizzled [q][v], 4x4KB

  int t = threadIdx.x, lane = t & 63, w = t >> 6;
  float* Ab = A + (size_t)b * LQ * LV + (size_t)qs * 32 * LV;
  const ushort* Vb = VhT + (size_t)b * NH * LV;

  const int prow = t >> 4, pc = (t & 15) << 2;   // 4 f32 per thread per chunk
  float* aaddr = Ab + (size_t)prow * LV + pc;
  const int poff = (prow * 128 + pc * 2) ^ ((prow & 7) << 4);

  // stats combine: 16 threads/row, one 128-col partial each, 16-lane reduce
  {
    int row = t >> 4, seg = t & 15;
    float2 p = PS[((size_t)(b * LQ) + qs * 32 + row) * 16 + seg];
    float M = p.x, s = p.y;
    #pragma unroll
    for (int off = 1; off < 16; off <<= 1) {
      float mo = __shfl_xor(M, off), so = __shfl_xor(s, off);
      float mn = fmaxf(M, mo);
      s = s * __expf(M - mn) + so * __expf(mo - mn);
      M = mn;
    }
    if (seg == 0) { lm[row] = M; li[row] = 1.f / s; }
  }
  __syncthreads();

  const float pm = lm[prow], pinv = li[prow];

#define PRODUCE(xv, v0, buf)                                                \
  {                                                                         \
    float4 p;                                                               \
    p.x = __expf((xv).x - pm) * pinv; p.y = __expf((xv).y - pm) * pinv;     \
    p.z = __expf((xv).z - pm) * pinv; p.w = __expf((xv).w - pm) * pinv;     \
    *reinterpret_cast<float4*>(aaddr + (v0)) = p;                           \
    ushort4 pk;                                                             \
    pk.x = f32_bf16(p.x); pk.y = f32_bf16(p.y);                             \
    pk.z = f32_bf16(p.z); pk.w = f32_bf16(p.w);                             \
    *reinterpret_cast<ushort4*>((char*)&sP[buf][0] + poff) = pk;            \
  }

  // prologue: chunks 0,1 -> sP[0],sP[1]; prefetch chunks 2,3
  float4 x0 = *reinterpret_cast<const float4*>(aaddr);
  float4 x1 = *reinterpret_cast<const float4*>(aaddr + 64);
  PRODUCE(x0, 0, 0);
  PRODUCE(x1, 64, 1);
  x0 = *reinterpret_cast<const float4*>(aaddr + 128);
  x1 = *reinterpret_cast<const float4*>(aaddr + 192);
  __syncthreads();

  f32x4 acc[2][2] = {};
  const int NP = LV / 128;  // 16 pairs

  for (int p = 0; p < NP; ++p) {
    const int cur = (p & 1) << 1;        // bufs cur, cur+1 hold pair p
    const int nxt = cur ^ 2;
    const int v0 = p * 128;
    if (p + 1 < NP) {
      PRODUCE(x0, v0 + 128, nxt);
      PRODUCE(x1, v0 + 192, nxt + 1);
    }
    if (p + 2 < NP) {
      x0 = *reinterpret_cast<const float4*>(aaddr + v0 + 256);
      x1 = *reinterpret_cast<const float4*>(aaddr + v0 + 320);
    }

    #pragma unroll
    for (int c = 0; c < 2; ++c) {
      #pragma unroll
      for (int ks = 0; ks < 2; ++ks) {
        int vbyte = ks * 64 + ((lane >> 4) << 4);
        bf16x8 pa[2];
        #pragma unroll
        for (int i2 = 0; i2 < 2; ++i2) {
          int arow = i2 * 16 + (lane & 15);
          pa[i2] = *reinterpret_cast<const bf16x8*>(
              (char*)&sP[cur + c][0] + ((arow * 128 + vbyte) ^ ((arow & 7) << 4)));
        }
        #pragma unroll
        for (int n = 0; n < 2; ++n) {
          int hrow = w * 32 + n * 16 + (lane & 15);
          bf16x8 vb = *reinterpret_cast<const bf16x8*>(
              Vb + (size_t)hrow * LV + v0 + c * 64 + ks * 32 + ((lane >> 4) << 3));
          #pragma unroll
          for (int i2 = 0; i2 < 2; ++i2)
            acc[i2][n] = __builtin_amdgcn_mfma_f32_16x16x32_bf16(pa[i2], vb, acc[i2][n], 0, 0, 0);
        }
      }
    }
    __syncthreads();
  }
#undef PRODUCE

  float* Cb = C + ((size_t)b * LQ + qs * 32) * NH + w * 32;
  int rb = (lane >> 4) << 2, c0 = lane & 15;
  #pragma unroll
  for (int i2 = 0; i2 < 2; ++i2)
    #pragma unroll
    for (int j = 0; j < 4; ++j)
      #pragma unroll
      for (int n = 0; n < 2; ++n)
        Cb[(size_t)(i2 * 16 + rb + j) * NH + n * 16 + c0] = acc[i2][n][j];
}

// ============================ FALLBACK PATH (round-0) ======================

__global__ __launch_bounds__(256) void k_scores_fb(
    const float* __restrict__ Q, const float* __restrict__ V,
    float* __restrict__ S) {
  int id = blockIdx.x;
  int b = id & 7;
  int inner = id >> 3;
  int qt = inner & 31;
  int vt = inner >> 5;
  __shared__ ushort sQh[64 * 64], sQl[64 * 64], sVh[64 * 64], sVl[64 * 64];
  const float* Qb = Q + (size_t)(b * LQ + qt * 64) * NH;
  const float* Vb = V + (size_t)(b * LV + vt * 64) * NH;
  const int t = threadIdx.x;
  const int lane = t & 63;
  const int w = t >> 6;
  f32x4 acc[4] = {};
  const int row0 = t >> 4;
  const int col4 = (t & 15) << 2;
  for (int kc = 0; kc < 4; ++kc) {
    #pragma unroll
    for (int it = 0; it < 4; ++it) {
      int row = row0 + (it << 4);
      const float4 qx = *reinterpret_cast<const float4*>(Qb + (size_t)row * NH + kc * 64 + col4);
      const float4 vx = *reinterpret_cast<const float4*>(Vb + (size_t)row * NH + kc * 64 + col4);
      int off = ((row * 128 + col4 * 2) ^ ((row & 7) << 4)) >> 1;
      ushort4 h, l;
      h.x = f32_bf16(qx.x); l.x = f32_bf16(qx.x - bf16_f32(h.x));
      h.y = f32_bf16(qx.y); l.y = f32_bf16(qx.y - bf16_f32(h.y));
      h.z = f32_bf16(qx.z); l.z = f32_bf16(qx.z - bf16_f32(h.z));
      h.w = f32_bf16(qx.w); l.w = f32_bf16(qx.w - bf16_f32(h.w));
      *reinterpret_cast<ushort4*>(&sQh[off]) = h;
      *reinterpret_cast<ushort4*>(&sQl[off]) = l;
      h.x = f32_bf16(vx.x); l.x = f32_bf16(vx.x - bf16_f32(h.x));
      h.y = f32_bf16(vx.y); l.y = f32_bf16(vx.y - bf16_f32(h.y));
      h.z = f32_bf16(vx.z); l.z = f32_bf16(vx.z - bf16_f32(h.z));
      h.w = f32_bf16(vx.w); l.w = f32_bf16(vx.w - bf16_f32(h.w));
      *reinterpret_cast<ushort4*>(&sVh[off]) = h;
      *reinterpret_cast<ushort4*>(&sVl[off]) = l;
    }
    __syncthreads();
    int arow = (w << 4) + (lane & 15);
    int abase = arow * 128;
    int aswz = (arow & 7) << 4;
    #pragma unroll
    for (int ks = 0; ks < 2; ++ks) {
      int koffB = (ks << 6) + ((lane >> 4) << 4);
      int aoff = ((abase + koffB) ^ aswz) >> 1;
      bf16x8 ah = *reinterpret_cast<const bf16x8*>(&sQh[aoff]);
      bf16x8 al = *reinterpret_cast<const bf16x8*>(&sQl[aoff]);
      #pragma unroll
      for (int n = 0; n < 4; ++n) {
        int brow = (n << 4) + (lane & 15);
        int boff = (((brow * 128) + koffB) ^ ((brow & 7) << 4)) >> 1;
        bf16x8 bh = *reinterpret_cast<const bf16x8*>(&sVh[boff]);
        bf16x8 bl = *reinterpret_cast<const bf16x8*>(&sVl[boff]);
        acc[n] = __builtin_amdgcn_mfma_f32_16x16x32_bf16(ah, bh, acc[n], 0, 0, 0);
        acc[n] = __builtin_amdgcn_mfma_f32_16x16x32_bf16(ah, bl, acc[n], 0, 0, 0);
        acc[n] = __builtin_amdgcn_mfma_f32_16x16x32_bf16(al, bh, acc[n], 0, 0, 0);
      }
    }
    __syncthreads();
  }
  float* Sp = S + (size_t)b * LQ * LV + (size_t)(qt * 64) * LV + vt * 64;
  int rbase = (w << 4) + ((lane >> 4) << 2);
  int c0 = lane & 15;
  #pragma unroll
  for (int n = 0; n < 4; ++n)
    #pragma unroll
    for (int j = 0; j < 4; ++j)
      Sp[(size_t)(rbase + j) * LV + (n << 4) + c0] = acc[n][j];
}

__global__ __launch_bounds__(256) void k_stats_fb(const float* __restrict__ S,
                                                  float* __restrict__ ml) {
  const size_t r = blockIdx.x;
  const float* row = S + r * LV;
  int t = threadIdx.x;
  float4 a = *reinterpret_cast<const float4*>(row + (t << 2));
  float4 c = *reinterpret_cast<const float4*>(row + 1024 + (t << 2));
  float m = fmaxf(fmaxf(fmaxf(a.x, a.y), fmaxf(a.z, a.w)),
                  fmaxf(fmaxf(c.x, c.y), fmaxf(c.z, c.w)));
  #pragma unroll
  for (int off = 32; off; off >>= 1) m = fmaxf(m, __shfl_xor(m, off));
  __shared__ float redm[4];
  __shared__ float reds[4];
  if ((t & 63) == 0) redm[t >> 6] = m;
  __syncthreads();
  m = fmaxf(fmaxf(redm[0], redm[1]), fmaxf(redm[2], redm[3]));
  float s = __expf(a.x - m) + __expf(a.y - m) + __expf(a.z - m) + __expf(a.w - m)
          + __expf(c.x - m) + __expf(c.y - m) + __expf(c.z - m) + __expf(c.w - m);
  #pragma unroll
  for (int off = 32; off; off >>= 1) s += __shfl_xor(s, off);
  if ((t & 63) == 0) reds[t >> 6] = s;
  __syncthreads();
  if (t == 0) {
    float tot = reds[0] + reds[1] + reds[2] + reds[3];
    ml[2 * r] = m;
    ml[2 * r + 1] = 1.0f / tot;
  }
}

__global__ __launch_bounds__(256) void k_ctx_fb(
    const float* __restrict__ V, const float* __restrict__ ml,
    float* __restrict__ A, float* __restrict__ C) {
  int id = blockIdx.x;
  int b = id & 7;
  int qt = id >> 3;
  __shared__ ushort sP[32 * 40];
  __shared__ ushort sVT[256 * 40];
  __shared__ float lmv[32], liv[32];
  int t = threadIdx.x;
  int lane = t & 63;
  int w = t >> 6;
  int wr = w >> 1, wh = w & 1;
  if (t < 32) {
    size_t r = (size_t)b * LQ + qt * 32 + t;
    lmv[t] = ml[2 * r];
    liv[t] = ml[2 * r + 1];
  }
  __syncthreads();
  f32x4 acc[8] = {};
  float* Ab = A + (size_t)b * LQ * LV + (size_t)(qt * 32) * LV;
  const float* Vb = V + (size_t)b * LV * NH;
  const int prow = t >> 3;
  const int pv4 = (t & 7) << 2;
  for (int v0 = 0; v0 < LV; v0 += 32) {
    {
      float* addr = Ab + (size_t)prow * LV + v0 + pv4;
      float4 s4 = *reinterpret_cast<const float4*>(addr);
      float m = lmv[prow], inv = liv[prow];
      float4 p4;
      p4.x = __expf(s4.x - m) * inv;
      p4.y = __expf(s4.y - m) * inv;
      p4.z = __expf(s4.z - m) * inv;
      p4.w = __expf(s4.w - m) * inv;
      *reinterpret_cast<float4*>(addr) = p4;
      ushort4 pb;
      pb.x = f32_bf16(p4.x); pb.y = f32_bf16(p4.y);
      pb.z = f32_bf16(p4.z); pb.w = f32_bf16(p4.w);
      *reinterpret_cast<ushort4*>(&sP[prow * 40 + pv4]) = pb;
    }
    #pragma unroll 4
    for (int vl = 0; vl < 32; ++vl) {
      float x = Vb[(size_t)(v0 + vl) * NH + t];
      sVT[t * 40 + vl] = f32_bf16(x);
    }
    __syncthreads();
    bf16x8 pa = *reinterpret_cast<const bf16x8*>(
        &sP[((wr << 4) + (lane & 15)) * 40 + ((lane >> 4) << 3)]);
    #pragma unroll
    for (int n = 0; n < 8; ++n) {
      int hrow = (wh << 7) + (n << 4) + (lane & 15);
      bf16x8 vb = *reinterpret_cast<const bf16x8*>(
          &sVT[hrow * 40 + ((lane >> 4) << 3)]);
      acc[n] = __builtin_amdgcn_mfma_f32_16x16x32_bf16(pa, vb, acc[n], 0, 0, 0);
    }
    __syncthreads();
  }
  float* Cb = C + ((size_t)b * LQ + qt * 32) * NH;
  int rbase = (wr << 4) + ((lane >> 4) << 2);
  int c0 = lane & 15;
  #pragma unroll
  for (int n = 0; n < 8; ++n)
    #pragma unroll
    for (int j = 0; j < 4; ++j)
      Cb[(size_t)(rbase + j) * NH + (wh << 7) + (n << 4) + c0] = acc[n][j];
}

// ===========================================================================

extern "C" void kernel_launch(void* const* d_in, const int* in_sizes, int n_in,
                              void* d_out, int out_size, void* d_ws, size_t ws_size,
                              hipStream_t stream) {
  const float* Q = (const float*)d_in[0];
  const float* V = (const float*)d_in[1];
  float* out = (float*)d_out;
  float* C = out;                                  // context: 8*2048*256
  float* A = out + (size_t)NB * LQ * NH;           // attn:    8*2048*2048

  const size_t NE = (size_t)NB * LQ * NH;          // 4,194,304 elems
  const size_t PSN = (size_t)NB * LQ * 16;         // 262,144 float2
  const size_t need = NE * 2 * 5 + PSN * 8;        // ≈ 42 MiB
  const int DYN_LDS = 2 * 4 * 256 * 32 * 2;        // 131072 B

  bool big_lds_ok =
      hipFuncSetAttribute((const void*)k_scores6,
                          hipFuncAttributeMaxDynamicSharedMemorySize,
                          DYN_LDS) == hipSuccess;

  if (ws_size >= need && big_lds_ok) {
    ushort* Qh  = (ushort*)d_ws;
    ushort* Ql  = Qh + NE;
    ushort* Vh  = Ql + NE;
    ushort* Vl  = Vh + NE;
    ushort* VhT = Vl + NE;
    float2* PS  = (float2*)(VhT + NE);
    k_prepQ<<<dim3(NE / 4 / 256), dim3(256), 0, stream>>>(Q, Qh, Ql);
    k_prepV<<<dim3(NB * 32 * 4), dim3(256), 0, stream>>>(V, Vh, Vl, VhT);
    k_scores6<<<dim3(NB * 8 * 8), dim3(512), DYN_LDS, stream>>>(Qh, Ql, Vh, Vl, A, PS);
    k_ctx8<<<dim3(NB * 64), dim3(512), 0, stream>>>(VhT, PS, A, C);
  } else {
    float* ml = (float*)d_ws;                      // 128 KB fallback scratch
    k_scores_fb<<<dim3(NB * 32 * 32), dim3(256), 0, stream>>>(Q, V, A);
    k_stats_fb<<<dim3(NB * LQ), dim3(256), 0, stream>>>(A, ml);
    k_ctx_fb<<<dim3(NB * 64), dim3(256), 0, stream>>>(V, ml, A, C);
  }
}